// Round 12
// baseline (394.832 us; speedup 1.0000x reference)
//
#include <hip/hip_runtime.h>
#include <stdint.h>

// out = (adj @ (X@W + b)) / rowsum(adj)
// B=8, N=4096, C_IN=C_OUT=512, all fp32 in/out. bf16 MFMA internally.
// ws: hT bf16 [8][512][4096] (32 MiB), Wt bf16 [512][512] after.

typedef __attribute__((ext_vector_type(4))) float  f32x4;
typedef __attribute__((ext_vector_type(8))) __bf16 bf16x8;
typedef __attribute__((ext_vector_type(4))) __bf16 bf16x4;

// ---------------- K0: Wt[n][k] = bf16(W[k][n]), 512x512 ----------------
__global__ void __launch_bounds__(256) k_wt(const float* __restrict__ W,
                                            __bf16* __restrict__ Wt) {
  __shared__ __bf16 t[64][65];
  const int k0 = blockIdx.x * 64, n0 = blockIdx.y * 64;
  const int tid = threadIdx.x;
  const int r = tid >> 2, c4 = (tid & 3) * 16;
#pragma unroll
  for (int j = 0; j < 4; ++j) {
    f32x4 v = *reinterpret_cast<const f32x4*>(W + (size_t)(k0 + r) * 512 + n0 + c4 + j * 4);
#pragma unroll
    for (int q = 0; q < 4; ++q) t[c4 + j * 4 + q][r] = (__bf16)v[q];
  }
  __syncthreads();
#pragma unroll
  for (int j = 0; j < 4; ++j) {
    bf16x4 o;
#pragma unroll
    for (int q = 0; q < 4; ++q) o[q] = t[r][c4 + j * 4 + q];
    *reinterpret_cast<bf16x4*>(Wt + (size_t)(n0 + r) * 512 + k0 + c4 + j * 4) = o;
  }
}

// ---------------- K1: proj  h = X@W + b, stored transposed as hT[b][o][m] bf16 -----
__global__ void __launch_bounds__(256) k_proj(const float* __restrict__ X,
                                              const __bf16* __restrict__ Wt,
                                              const float* __restrict__ bias,
                                              __bf16* __restrict__ hT) {
  __shared__ __attribute__((aligned(16))) __bf16 Xs[128][72];
  __shared__ __attribute__((aligned(16))) __bf16 Ws[128][72];
  const int n0 = blockIdx.x * 128;
  const int m0 = blockIdx.y * 128;
  const int tid = threadIdx.x;
  const int lane = tid & 63, w = tid >> 6;
  const int wr = w >> 1, wc = w & 1;
  const int srow = tid >> 1, scb = (tid & 1) * 32;

  f32x4 acc[4][4] = {};

  for (int k0 = 0; k0 < 512; k0 += 64) {
    const float* xp = X + (size_t)(m0 + srow) * 512 + k0 + scb;
    f32x4 xv[8];
#pragma unroll
    for (int j = 0; j < 8; ++j) xv[j] = *reinterpret_cast<const f32x4*>(xp + j * 4);
#pragma unroll
    for (int q = 0; q < 4; ++q) {
      bf16x8 o;
#pragma unroll
      for (int e = 0; e < 8; ++e) { const int idx = q * 8 + e; o[e] = (__bf16)xv[idx >> 2][idx & 3]; }
      *reinterpret_cast<bf16x8*>(&Xs[srow][scb + q * 8]) = o;
    }
    const __bf16* wp = Wt + (size_t)(n0 + srow) * 512 + k0 + scb;
#pragma unroll
    for (int q = 0; q < 4; ++q)
      *reinterpret_cast<bf16x8*>(&Ws[srow][scb + q * 8]) =
          *reinterpret_cast<const bf16x8*>(wp + q * 8);
    __syncthreads();

    for (int kk = 0; kk < 64; kk += 32) {
      const int ko = kk + ((lane >> 4) << 3);
      bf16x8 a[4], bb[4];
#pragma unroll
      for (int i = 0; i < 4; ++i)
        a[i] = *reinterpret_cast<const bf16x8*>(&Xs[wr * 64 + i * 16 + (lane & 15)][ko]);
#pragma unroll
      for (int j = 0; j < 4; ++j)
        bb[j] = *reinterpret_cast<const bf16x8*>(&Ws[wc * 64 + j * 16 + (lane & 15)][ko]);
#pragma unroll
      for (int i = 0; i < 4; ++i)
#pragma unroll
        for (int j = 0; j < 4; ++j)
          acc[i][j] = __builtin_amdgcn_mfma_f32_16x16x32_bf16(a[i], bb[j], acc[i][j], 0, 0, 0);
    }
    __syncthreads();
  }

  float bj[4];
#pragma unroll
  for (int j = 0; j < 4; ++j) bj[j] = bias[n0 + wc * 64 + j * 16 + (lane & 15)];
  const int batch = m0 >> 12;
  const int mloc0 = (m0 & 4095) + wr * 64;
#pragma unroll
  for (int i = 0; i < 4; ++i) {
    const int m_in = mloc0 + i * 16 + ((lane >> 4) << 2);
#pragma unroll
    for (int j = 0; j < 4; ++j) {
      const int n = n0 + wc * 64 + j * 16 + (lane & 15);
      bf16x4 o;
#pragma unroll
      for (int r = 0; r < 4; ++r) o[r] = (__bf16)(acc[i][j][r] + bj[j]);
      *reinterpret_cast<bf16x4*>(hT + ((size_t)batch * 512 + n) * 4096 + m_in) = o;
    }
  }
}

// ---------------- K2: aggregation, B direct-from-L2 (no Hs staging) ---------------
// Catalog lesson m169: don't LDS-stage data that is cache-resident. hT slice =
// 4 MiB = exactly one XCD's L2 (batch<->XCD swizzle; R9 FETCH proved residency).
// B-fragments (lane l&15 -> hT row, (l>>4)*8 -> contiguous k) are plain 16 B
// global loads, full 64 B line utilization. LDS keeps only As (2x16 KiB dbuf).
// Per tile: issue adj(t+1) NT -> compute (A from LDS, B from L2) -> write
// As(t+1) -> __syncthreads(). NO inline-asm waits anywhere: every dependency
// is compiler-tracked precisely (eliminates the R7/R10 race class).
// 16 waves (2x8), wave tile 64x64, BM=128 x BN=512, adj read exactly once.
__global__ void __launch_bounds__(1024, 4) k_agg(const float* __restrict__ adj,
                                                 const __bf16* __restrict__ hT,
                                                 float* __restrict__ out) {
  __shared__ __attribute__((aligned(16))) char lds[33280];  // As dbuf 2x16K + 512 B deg
  char* As0 = lds;
  char* As1 = lds + 16384;

  const int bx = ((int)blockIdx.x & 7) * 32 + ((int)blockIdx.x >> 3);  // XCD x <-> batch x
  const int batch = bx >> 5;
  const int m0 = (bx & 31) * 128;
  const int tid = threadIdx.x;
  const int lane = tid & 63, w = tid >> 6;
  const int wr = w >> 3, wc = w & 7;  // wave tile: rows wr*64, cols wc*64

  const float*  adjb = adj + (size_t)batch * 4096 * 4096;
  const __bf16* hTb  = hT + (size_t)batch * 512 * 4096;
  float* outb = out + (size_t)batch * 4096 * 512;

  // A staging: thread -> row tid>>3, 8 cols from (tid&7)*8, XOR-swizzled write
  const int arow = tid >> 3;
  const int acb  = (tid & 7) * 8;
  const int aw   = arow * 128 + ((acb * 2) ^ ((arow & 7) << 4));
  const float* adjrow = adjb + (size_t)(m0 + arow) * 4096 + acb;

  // As fragment-read swizzle (row&7 == lane&7 for all frag rows)
  const int koffbase = (lane >> 4) << 3;
  const int kswz = (lane & 7) << 4;

  // B direct-load base: row = wc*64 + (lane&15), k-offset (lane>>4)*8
  const __bf16* hTw = hTb + (size_t)(wc * 64 + (lane & 15)) * 4096 + ((lane >> 4) << 3);

  f32x4 acc[4][4] = {};
  float pdeg = 0.f;
  f32x4 av0, av1;

  auto load_adj = [&](int k0) {  // NT: single-use stream, protect hT L2 residency
    av0 = __builtin_nontemporal_load(reinterpret_cast<const f32x4*>(adjrow + k0));
    av1 = __builtin_nontemporal_load(reinterpret_cast<const f32x4*>(adjrow + k0 + 4));
  };
  auto write_as = [&](char* An) {  // compiler waits av precisely (vmcnt counted)
    bf16x8 o0;
#pragma unroll
    for (int e = 0; e < 4; ++e) o0[e] = (__bf16)av0[e];
#pragma unroll
    for (int e = 0; e < 4; ++e) o0[4 + e] = (__bf16)av1[e];
    pdeg += av0[0] + av0[1] + av0[2] + av0[3] + av1[0] + av1[1] + av1[2] + av1[3];
    *reinterpret_cast<bf16x8*>(An + aw) = o0;
  };
  auto compute = [&](const char* Ac, int kbase) {
#pragma unroll
    for (int kk = 0; kk < 64; kk += 32) {
      const int ko2 = ((kk + koffbase) * 2) ^ kswz;
      bf16x8 a[4], bb[4];
#pragma unroll
      for (int i = 0; i < 4; ++i) {
        const int row = wr * 64 + i * 16 + (lane & 15);
        a[i] = *reinterpret_cast<const bf16x8*>(Ac + row * 128 + ko2);
      }
#pragma unroll
      for (int j = 0; j < 4; ++j)  // B from L2-resident hT; j*16 rows apart
        bb[j] = *reinterpret_cast<const bf16x8*>(hTw + (size_t)j * 16 * 4096 + kbase + kk);
#pragma unroll
      for (int i = 0; i < 4; ++i)
#pragma unroll
        for (int j = 0; j < 4; ++j)
          acc[i][j] = __builtin_amdgcn_mfma_f32_16x16x32_bf16(a[i], bb[j], acc[i][j], 0, 0, 0);
    }
  };

  // ---- prologue: stage As(0) ----
  load_adj(0);
  write_as(As0);
  __syncthreads();

  // ---- main loop: 1 syncthreads per tile, As dbuf, B streamed from L2 ----
  for (int t = 0; t < 63; ++t) {
    const int cur = t & 1;
    const char* Ac = cur ? As1 : As0;
    char* An = cur ? As0 : As1;

    load_adj((t + 1) * 64);  // issued before compute: HBM latency hides under it
    compute(Ac, t * 64);
    write_as(An);            // WAR-safe: An's readers finished at previous barrier
    __syncthreads();
  }
  compute(As1, 63 * 64);     // t=63

  // ---- degree: 8 partials per row, shfl + LDS exchange (reuse As region) ----
  float d = pdeg;
  d += __shfl_xor(d, 1, 64);
  d += __shfl_xor(d, 2, 64);
  d += __shfl_xor(d, 4, 64);
  __syncthreads();  // all compute done; As region free for reuse
  if ((tid & 7) == 0) reinterpret_cast<float*>(lds)[arow] = d;
  __syncthreads();
  const float* degf = reinterpret_cast<const float*>(lds);

  // ---- epilogue: divide, NT store fp32 ----
#pragma unroll
  for (int i = 0; i < 4; ++i) {
    const int rbase = wr * 64 + i * 16 + ((lane >> 4) << 2);
    float rd[4];
#pragma unroll
    for (int r = 0; r < 4; ++r) rd[r] = 1.0f / degf[rbase + r];
#pragma unroll
    for (int j = 0; j < 4; ++j) {
      const int o = wc * 64 + j * 16 + (lane & 15);
#pragma unroll
      for (int r = 0; r < 4; ++r)
        __builtin_nontemporal_store(acc[i][j][r] * rd[r],
                                    &outb[(size_t)(m0 + rbase + r) * 512 + o]);
    }
  }
}

extern "C" void kernel_launch(void* const* d_in, const int* in_sizes, int n_in,
                              void* d_out, int out_size, void* d_ws, size_t ws_size,
                              hipStream_t stream) {
  (void)in_sizes; (void)n_in; (void)out_size; (void)ws_size;
  const float* X    = (const float*)d_in[0];  // [8,4096,512]
  const float* adj  = (const float*)d_in[1];  // [8,4096,4096]
  const float* W    = (const float*)d_in[2];  // [512,512]
  const float* bias = (const float*)d_in[3];  // [512]
  float* out = (float*)d_out;                 // [8,4096,512] fp32

  char* ws = (char*)d_ws;
  __bf16* hT = (__bf16*)ws;                                   // 32 MiB
  __bf16* Wt = (__bf16*)(ws + (size_t)32 * 1024 * 1024);      // 512 KiB

  k_wt<<<dim3(8, 8), 256, 0, stream>>>(W, Wt);
  k_proj<<<dim3(4, 256), 256, 0, stream>>>(X, Wt, bias, hT);
  k_agg<<<dim3(256), 1024, 0, stream>>>(adj, hT, out);
}

// Round 13
// 392.288 us; speedup vs baseline: 1.0065x; 1.0065x over previous
//
#include <hip/hip_runtime.h>
#include <stdint.h>

// out = (adj @ (X@W + b)) / rowsum(adj)
// B=8, N=4096, C_IN=C_OUT=512, all fp32 in/out. bf16 MFMA internally.
// ws: hT bf16 [8][512][4096] (32 MiB), Wt bf16 [512][512] after.

typedef __attribute__((ext_vector_type(4))) float  f32x4;
typedef __attribute__((ext_vector_type(8))) __bf16 bf16x8;
typedef __attribute__((ext_vector_type(4))) __bf16 bf16x4;

// ---------------- K0: Wt[n][k] = bf16(W[k][n]), 512x512 ----------------
__global__ void __launch_bounds__(256) k_wt(const float* __restrict__ W,
                                            __bf16* __restrict__ Wt) {
  __shared__ __bf16 t[64][65];
  const int k0 = blockIdx.x * 64, n0 = blockIdx.y * 64;
  const int tid = threadIdx.x;
  const int r = tid >> 2, c4 = (tid & 3) * 16;
#pragma unroll
  for (int j = 0; j < 4; ++j) {
    f32x4 v = *reinterpret_cast<const f32x4*>(W + (size_t)(k0 + r) * 512 + n0 + c4 + j * 4);
#pragma unroll
    for (int q = 0; q < 4; ++q) t[c4 + j * 4 + q][r] = (__bf16)v[q];
  }
  __syncthreads();
#pragma unroll
  for (int j = 0; j < 4; ++j) {
    bf16x4 o;
#pragma unroll
    for (int q = 0; q < 4; ++q) o[q] = t[r][c4 + j * 4 + q];
    *reinterpret_cast<bf16x4*>(Wt + (size_t)(n0 + r) * 512 + k0 + c4 + j * 4) = o;
  }
}

// ---------------- K1: proj  h = X@W + b, stored transposed as hT[b][o][m] bf16 -----
__global__ void __launch_bounds__(256) k_proj(const float* __restrict__ X,
                                              const __bf16* __restrict__ Wt,
                                              const float* __restrict__ bias,
                                              __bf16* __restrict__ hT) {
  __shared__ __attribute__((aligned(16))) __bf16 Xs[128][72];
  __shared__ __attribute__((aligned(16))) __bf16 Ws[128][72];
  const int n0 = blockIdx.x * 128;
  const int m0 = blockIdx.y * 128;
  const int tid = threadIdx.x;
  const int lane = tid & 63, w = tid >> 6;
  const int wr = w >> 1, wc = w & 1;
  const int srow = tid >> 1, scb = (tid & 1) * 32;

  f32x4 acc[4][4] = {};

  for (int k0 = 0; k0 < 512; k0 += 64) {
    const float* xp = X + (size_t)(m0 + srow) * 512 + k0 + scb;
    f32x4 xv[8];
#pragma unroll
    for (int j = 0; j < 8; ++j) xv[j] = *reinterpret_cast<const f32x4*>(xp + j * 4);
#pragma unroll
    for (int q = 0; q < 4; ++q) {
      bf16x8 o;
#pragma unroll
      for (int e = 0; e < 8; ++e) { const int idx = q * 8 + e; o[e] = (__bf16)xv[idx >> 2][idx & 3]; }
      *reinterpret_cast<bf16x8*>(&Xs[srow][scb + q * 8]) = o;
    }
    const __bf16* wp = Wt + (size_t)(n0 + srow) * 512 + k0 + scb;
#pragma unroll
    for (int q = 0; q < 4; ++q)
      *reinterpret_cast<bf16x8*>(&Ws[srow][scb + q * 8]) =
          *reinterpret_cast<const bf16x8*>(wp + q * 8);
    __syncthreads();

    for (int kk = 0; kk < 64; kk += 32) {
      const int ko = kk + ((lane >> 4) << 3);
      bf16x8 a[4], bb[4];
#pragma unroll
      for (int i = 0; i < 4; ++i)
        a[i] = *reinterpret_cast<const bf16x8*>(&Xs[wr * 64 + i * 16 + (lane & 15)][ko]);
#pragma unroll
      for (int j = 0; j < 4; ++j)
        bb[j] = *reinterpret_cast<const bf16x8*>(&Ws[wc * 64 + j * 16 + (lane & 15)][ko]);
#pragma unroll
      for (int i = 0; i < 4; ++i)
#pragma unroll
        for (int j = 0; j < 4; ++j)
          acc[i][j] = __builtin_amdgcn_mfma_f32_16x16x32_bf16(a[i], bb[j], acc[i][j], 0, 0, 0);
    }
    __syncthreads();
  }

  float bj[4];
#pragma unroll
  for (int j = 0; j < 4; ++j) bj[j] = bias[n0 + wc * 64 + j * 16 + (lane & 15)];
  const int batch = m0 >> 12;
  const int mloc0 = (m0 & 4095) + wr * 64;
#pragma unroll
  for (int i = 0; i < 4; ++i) {
    const int m_in = mloc0 + i * 16 + ((lane >> 4) << 2);
#pragma unroll
    for (int j = 0; j < 4; ++j) {
      const int n = n0 + wc * 64 + j * 16 + (lane & 15);
      bf16x4 o;
#pragma unroll
      for (int r = 0; r < 4; ++r) o[r] = (__bf16)(acc[i][j][r] + bj[j]);
      *reinterpret_cast<bf16x4*>(hT + ((size_t)batch * 512 + n) * 4096 + m_in) = o;
    }
  }
}

// ---------------- K2: aggregation, B from L2, NO per-tile VMEM drain ---------------
// R12 post-mortem: __syncthreads() emits vmcnt(0) before s_barrier -> flushed the
// whole B+adj VMEM stream every tile (13k cy/tile, all pipes idle). This kernel
// has NO global_load_lds: all VMEM lands in registers (compiler-tracked), LDS As
// is written only by ds_write. So the barrier needs ONLY lgkmcnt(0) -- raw
// s_barrier without vmcnt. B-loads and the adj stream flow across tiles; 4
// waves/SIMD stagger hides L2 latency.
// 16 waves (2x8), wave tile 64x64, BM=128 x BN=512 (adj read once), BK=64.
// LDS: As dbuf 2x16K only.
__global__ void __launch_bounds__(1024, 4) k_agg(const float* __restrict__ adj,
                                                 const __bf16* __restrict__ hT,
                                                 float* __restrict__ out) {
  __shared__ __attribute__((aligned(16))) char lds[33280];  // As dbuf 2x16K + deg
  char* As0 = lds;
  char* As1 = lds + 16384;

  const int bx = ((int)blockIdx.x & 7) * 32 + ((int)blockIdx.x >> 3);  // XCD x <-> batch x
  const int batch = bx >> 5;
  const int m0 = (bx & 31) * 128;
  const int tid = threadIdx.x;
  const int lane = tid & 63, w = tid >> 6;
  const int wr = w >> 3, wc = w & 7;  // wave tile: rows wr*64, cols wc*64

  const float*  adjb = adj + (size_t)batch * 4096 * 4096;
  const __bf16* hTb  = hT + (size_t)batch * 512 * 4096;
  float* outb = out + (size_t)batch * 4096 * 512;

  // A staging: thread -> row tid>>3, 8 cols from (tid&7)*8, XOR-swizzled write
  const int arow = tid >> 3;
  const int acb  = (tid & 7) * 8;
  const int aw   = arow * 128 + ((acb * 2) ^ ((arow & 7) << 4));
  const float* adjrow = adjb + (size_t)(m0 + arow) * 4096 + acb;

  // As fragment-read swizzle
  const int koffbase = (lane >> 4) << 3;
  const int kswz = (lane & 7) << 4;

  // B direct-load base: row = wc*64 + (lane&15), k-granule (lane>>4)*8
  const __bf16* hTw = hTb + (size_t)(wc * 64 + (lane & 15)) * 4096 + ((lane >> 4) << 3);

  f32x4 acc[4][4] = {};
  float pdeg = 0.f;
  f32x4 av0, av1;

  auto load_adj = [&](int k0) {  // NT: single-use stream, protect hT L2 residency
    av0 = __builtin_nontemporal_load(reinterpret_cast<const f32x4*>(adjrow + k0));
    av1 = __builtin_nontemporal_load(reinterpret_cast<const f32x4*>(adjrow + k0 + 4));
  };
  auto write_as = [&](char* An) {  // compiler waits av precisely (counted vmcnt)
    bf16x8 o0;
#pragma unroll
    for (int e = 0; e < 4; ++e) o0[e] = (__bf16)av0[e];
#pragma unroll
    for (int e = 0; e < 4; ++e) o0[4 + e] = (__bf16)av1[e];
    pdeg += av0[0] + av0[1] + av0[2] + av0[3] + av1[0] + av1[1] + av1[2] + av1[3];
    *reinterpret_cast<bf16x8*>(An + aw) = o0;
  };
  auto compute = [&](const char* Ac, int kbase) {
    // all 8 B loads issued up front (in flight together)
    bf16x8 b0[4], b1[4];
#pragma unroll
    for (int j = 0; j < 4; ++j)
      b0[j] = *reinterpret_cast<const bf16x8*>(hTw + (size_t)j * 16 * 4096 + kbase);
#pragma unroll
    for (int j = 0; j < 4; ++j)
      b1[j] = *reinterpret_cast<const bf16x8*>(hTw + (size_t)j * 16 * 4096 + kbase + 32);
    {
      const int ko2 = (koffbase * 2) ^ kswz;
      bf16x8 a[4];
#pragma unroll
      for (int i = 0; i < 4; ++i)
        a[i] = *reinterpret_cast<const bf16x8*>(Ac + (wr * 64 + i * 16 + (lane & 15)) * 128 + ko2);
#pragma unroll
      for (int i = 0; i < 4; ++i)
#pragma unroll
        for (int j = 0; j < 4; ++j)
          acc[i][j] = __builtin_amdgcn_mfma_f32_16x16x32_bf16(a[i], b0[j], acc[i][j], 0, 0, 0);
    }
    {
      const int ko2 = ((32 + koffbase) * 2) ^ kswz;
      bf16x8 a[4];
#pragma unroll
      for (int i = 0; i < 4; ++i)
        a[i] = *reinterpret_cast<const bf16x8*>(Ac + (wr * 64 + i * 16 + (lane & 15)) * 128 + ko2);
#pragma unroll
      for (int i = 0; i < 4; ++i)
#pragma unroll
        for (int j = 0; j < 4; ++j)
          acc[i][j] = __builtin_amdgcn_mfma_f32_16x16x32_bf16(a[i], b1[j], acc[i][j], 0, 0, 0);
    }
  };

  // ---- prologue: stage As(0) ----
  load_adj(0);
  write_as(As0);
  asm volatile("s_waitcnt lgkmcnt(0)" ::: "memory");
  __builtin_amdgcn_s_barrier();
  asm volatile("" ::: "memory");

  // ---- main loop: lgkm-only barrier per tile (NO vmcnt drain anywhere) ----
  for (int t = 0; t < 63; ++t) {
    const int cur = t & 1;
    const char* Ac = cur ? As1 : As0;
    char* An = cur ? As0 : As1;

    load_adj((t + 1) * 64);  // NT stream, consumed by write_as after compute
    compute(Ac, t * 64);     // B from L2, A from LDS
    write_as(An);            // WAR-safe: An's readers finished at previous barrier
    asm volatile("s_waitcnt lgkmcnt(0)" ::: "memory");  // publish ds_write only
    __builtin_amdgcn_s_barrier();
    asm volatile("" ::: "memory");
  }
  compute(As1, 63 * 64);     // t=63

  // ---- degree: 8 partials per row, shfl + LDS exchange (reuse As region) ----
  float d = pdeg;
  d += __shfl_xor(d, 1, 64);
  d += __shfl_xor(d, 2, 64);
  d += __shfl_xor(d, 4, 64);
  __syncthreads();  // all compute done; As region free for reuse
  if ((tid & 7) == 0) reinterpret_cast<float*>(lds)[arow] = d;
  __syncthreads();
  const float* degf = reinterpret_cast<const float*>(lds);

  // ---- epilogue: divide, NT store fp32 ----
#pragma unroll
  for (int i = 0; i < 4; ++i) {
    const int rbase = wr * 64 + i * 16 + ((lane >> 4) << 2);
    float rd[4];
#pragma unroll
    for (int r = 0; r < 4; ++r) rd[r] = 1.0f / degf[rbase + r];
#pragma unroll
    for (int j = 0; j < 4; ++j) {
      const int o = wc * 64 + j * 16 + (lane & 15);
#pragma unroll
      for (int r = 0; r < 4; ++r)
        __builtin_nontemporal_store(acc[i][j][r] * rd[r],
                                    &outb[(size_t)(m0 + rbase + r) * 512 + o]);
    }
  }
}

extern "C" void kernel_launch(void* const* d_in, const int* in_sizes, int n_in,
                              void* d_out, int out_size, void* d_ws, size_t ws_size,
                              hipStream_t stream) {
  (void)in_sizes; (void)n_in; (void)out_size; (void)ws_size;
  const float* X    = (const float*)d_in[0];  // [8,4096,512]
  const float* adj  = (const float*)d_in[1];  // [8,4096,4096]
  const float* W    = (const float*)d_in[2];  // [512,512]
  const float* bias = (const float*)d_in[3];  // [512]
  float* out = (float*)d_out;                 // [8,4096,512] fp32

  char* ws = (char*)d_ws;
  __bf16* hT = (__bf16*)ws;                                   // 32 MiB
  __bf16* Wt = (__bf16*)(ws + (size_t)32 * 1024 * 1024);      // 512 KiB

  k_wt<<<dim3(8, 8), 256, 0, stream>>>(W, Wt);
  k_proj<<<dim3(4, 256), 256, 0, stream>>>(X, Wt, bias, hT);
  k_agg<<<dim3(256), 1024, 0, stream>>>(adj, hT, out);
}

// Round 14
// 390.195 us; speedup vs baseline: 1.0119x; 1.0054x over previous
//
#include <hip/hip_runtime.h>
#include <stdint.h>

// out = (adj @ (X@W + b)) / rowsum(adj)
// B=8, N=4096, C_IN=C_OUT=512, all fp32 in/out. bf16 MFMA internally.
// ws: hTT bf16 [8][64][512][64] (m-blocked, 32 MiB), Wt bf16 [512][512] after.
// hTT[b][m>>6][o][m&63]: the agg GEMM's per-K-tile B operand is one contiguous
// 64 KiB block (row stride 128 B) -- fixes the 8 KiB-stride L2 channel aliasing
// that floored R4-R13 at ~6.5 cy per 64 B hT line.

typedef __attribute__((ext_vector_type(4))) float  f32x4;
typedef __attribute__((ext_vector_type(8))) __bf16 bf16x8;
typedef __attribute__((ext_vector_type(4))) __bf16 bf16x4;

// ---------------- K0: Wt[n][k] = bf16(W[k][n]), 512x512 ----------------
__global__ void __launch_bounds__(256) k_wt(const float* __restrict__ W,
                                            __bf16* __restrict__ Wt) {
  __shared__ __bf16 t[64][65];
  const int k0 = blockIdx.x * 64, n0 = blockIdx.y * 64;
  const int tid = threadIdx.x;
  const int r = tid >> 2, c4 = (tid & 3) * 16;
#pragma unroll
  for (int j = 0; j < 4; ++j) {
    f32x4 v = *reinterpret_cast<const f32x4*>(W + (size_t)(k0 + r) * 512 + n0 + c4 + j * 4);
#pragma unroll
    for (int q = 0; q < 4; ++q) t[c4 + j * 4 + q][r] = (__bf16)v[q];
  }
  __syncthreads();
#pragma unroll
  for (int j = 0; j < 4; ++j) {
    bf16x4 o;
#pragma unroll
    for (int q = 0; q < 4; ++q) o[q] = t[r][c4 + j * 4 + q];
    *reinterpret_cast<bf16x4*>(Wt + (size_t)(n0 + r) * 512 + k0 + c4 + j * 4) = o;
  }
}

// ---------------- K1: proj  h = X@W + b, stored m-blocked: hTT[b][m>>6][o][m&63] ----
__global__ void __launch_bounds__(256) k_proj(const float* __restrict__ X,
                                              const __bf16* __restrict__ Wt,
                                              const float* __restrict__ bias,
                                              __bf16* __restrict__ hTT) {
  __shared__ __attribute__((aligned(16))) __bf16 Xs[128][72];
  __shared__ __attribute__((aligned(16))) __bf16 Ws[128][72];
  const int n0 = blockIdx.x * 128;
  const int m0 = blockIdx.y * 128;
  const int tid = threadIdx.x;
  const int lane = tid & 63, w = tid >> 6;
  const int wr = w >> 1, wc = w & 1;
  const int srow = tid >> 1, scb = (tid & 1) * 32;

  f32x4 acc[4][4] = {};

  for (int k0 = 0; k0 < 512; k0 += 64) {
    const float* xp = X + (size_t)(m0 + srow) * 512 + k0 + scb;
    f32x4 xv[8];
#pragma unroll
    for (int j = 0; j < 8; ++j) xv[j] = *reinterpret_cast<const f32x4*>(xp + j * 4);
#pragma unroll
    for (int q = 0; q < 4; ++q) {
      bf16x8 o;
#pragma unroll
      for (int e = 0; e < 8; ++e) { const int idx = q * 8 + e; o[e] = (__bf16)xv[idx >> 2][idx & 3]; }
      *reinterpret_cast<bf16x8*>(&Xs[srow][scb + q * 8]) = o;
    }
    const __bf16* wp = Wt + (size_t)(n0 + srow) * 512 + k0 + scb;
#pragma unroll
    for (int q = 0; q < 4; ++q)
      *reinterpret_cast<bf16x8*>(&Ws[srow][scb + q * 8]) =
          *reinterpret_cast<const bf16x8*>(wp + q * 8);
    __syncthreads();

    for (int kk = 0; kk < 64; kk += 32) {
      const int ko = kk + ((lane >> 4) << 3);
      bf16x8 a[4], bb[4];
#pragma unroll
      for (int i = 0; i < 4; ++i)
        a[i] = *reinterpret_cast<const bf16x8*>(&Xs[wr * 64 + i * 16 + (lane & 15)][ko]);
#pragma unroll
      for (int j = 0; j < 4; ++j)
        bb[j] = *reinterpret_cast<const bf16x8*>(&Ws[wc * 64 + j * 16 + (lane & 15)][ko]);
#pragma unroll
      for (int i = 0; i < 4; ++i)
#pragma unroll
        for (int j = 0; j < 4; ++j)
          acc[i][j] = __builtin_amdgcn_mfma_f32_16x16x32_bf16(a[i], bb[j], acc[i][j], 0, 0, 0);
    }
    __syncthreads();
  }

  float bj[4];
#pragma unroll
  for (int j = 0; j < 4; ++j) bj[j] = bias[n0 + wc * 64 + j * 16 + (lane & 15)];
  const int batch = m0 >> 12;
  const int mloc0 = (m0 & 4095) + wr * 64;
  __bf16* hb = hTT + (size_t)batch * 4096 * 512;
#pragma unroll
  for (int i = 0; i < 4; ++i) {
    const int m_in = mloc0 + i * 16 + ((lane >> 4) << 2);  // 4 consecutive m
#pragma unroll
    for (int j = 0; j < 4; ++j) {
      const int n = n0 + wc * 64 + j * 16 + (lane & 15);
      bf16x4 o;
#pragma unroll
      for (int r = 0; r < 4; ++r) o[r] = (__bf16)(acc[i][j][r] + bj[j]);
      // m-blocked: [m>>6][o][m&63]
      *reinterpret_cast<bf16x4*>(hb + ((size_t)(m_in >> 6) * 512 + n) * 64 + (m_in & 63)) = o;
    }
  }
}

// ---------------- K2: aggregation, B direct from m-blocked L2-resident hTT --------
// Identical to R13 except B addressing (single-variable layout test).
// 16 waves (2x8), wave tile 64x64, BM=128 x BN=512 (adj read once), BK=64.
// LDS: As dbuf 2x16K only. lgkm-only barrier (no VMEM drain at barriers).
// B-load: one instr = 16 sequential 128 B rows (2 KiB contiguous span).
__global__ void __launch_bounds__(1024, 4) k_agg(const float* __restrict__ adj,
                                                 const __bf16* __restrict__ hTT,
                                                 float* __restrict__ out) {
  __shared__ __attribute__((aligned(16))) char lds[33280];  // As dbuf 2x16K + deg
  char* As0 = lds;
  char* As1 = lds + 16384;

  const int bx = ((int)blockIdx.x & 7) * 32 + ((int)blockIdx.x >> 3);  // XCD x <-> batch x
  const int batch = bx >> 5;
  const int m0 = (bx & 31) * 128;
  const int tid = threadIdx.x;
  const int lane = tid & 63, w = tid >> 6;
  const int wr = w >> 3, wc = w & 7;  // wave tile: rows wr*64, cols wc*64

  const float*  adjb = adj + (size_t)batch * 4096 * 4096;
  const __bf16* hb   = hTT + (size_t)batch * 4096 * 512;
  float* outb = out + (size_t)batch * 4096 * 512;

  // A staging: thread -> row tid>>3, 8 cols from (tid&7)*8, XOR-swizzled write
  const int arow = tid >> 3;
  const int acb  = (tid & 7) * 8;
  const int aw   = arow * 128 + ((acb * 2) ^ ((arow & 7) << 4));
  const float* adjrow = adjb + (size_t)(m0 + arow) * 4096 + acb;

  // As fragment-read swizzle
  const int koffbase = (lane >> 4) << 3;
  const int kswz = (lane & 7) << 4;

  // B base within a tile block: row o = wc*64 + (lane&15), granule (lane>>4)*8.
  // Tile t's block = hb + t*512*64 (contiguous 64 KiB).
  const __bf16* hbw = hb + (size_t)(wc * 64 + (lane & 15)) * 64 + ((lane >> 4) << 3);

  f32x4 acc[4][4] = {};
  float pdeg = 0.f;
  f32x4 av0, av1;

  auto load_adj = [&](int k0) {  // NT: single-use stream, protect hTT L2 residency
    av0 = __builtin_nontemporal_load(reinterpret_cast<const f32x4*>(adjrow + k0));
    av1 = __builtin_nontemporal_load(reinterpret_cast<const f32x4*>(adjrow + k0 + 4));
  };
  auto write_as = [&](char* An) {  // compiler waits av precisely (counted vmcnt)
    bf16x8 o0;
#pragma unroll
    for (int e = 0; e < 4; ++e) o0[e] = (__bf16)av0[e];
#pragma unroll
    for (int e = 0; e < 4; ++e) o0[4 + e] = (__bf16)av1[e];
    pdeg += av0[0] + av0[1] + av0[2] + av0[3] + av1[0] + av1[1] + av1[2] + av1[3];
    *reinterpret_cast<bf16x8*>(An + aw) = o0;
  };
  auto compute = [&](const char* Ac, int t) {
    const __bf16* bt = hbw + (size_t)t * 512 * 64;
    bf16x8 b0[4], b1[4];
#pragma unroll
    for (int j = 0; j < 4; ++j)
      b0[j] = *reinterpret_cast<const bf16x8*>(bt + (size_t)j * 16 * 64);
#pragma unroll
    for (int j = 0; j < 4; ++j)
      b1[j] = *reinterpret_cast<const bf16x8*>(bt + (size_t)j * 16 * 64 + 32);
    {
      const int ko2 = (koffbase * 2) ^ kswz;
      bf16x8 a[4];
#pragma unroll
      for (int i = 0; i < 4; ++i)
        a[i] = *reinterpret_cast<const bf16x8*>(Ac + (wr * 64 + i * 16 + (lane & 15)) * 128 + ko2);
#pragma unroll
      for (int i = 0; i < 4; ++i)
#pragma unroll
        for (int j = 0; j < 4; ++j)
          acc[i][j] = __builtin_amdgcn_mfma_f32_16x16x32_bf16(a[i], b0[j], acc[i][j], 0, 0, 0);
    }
    {
      const int ko2 = ((32 + koffbase) * 2) ^ kswz;
      bf16x8 a[4];
#pragma unroll
      for (int i = 0; i < 4; ++i)
        a[i] = *reinterpret_cast<const bf16x8*>(Ac + (wr * 64 + i * 16 + (lane & 15)) * 128 + ko2);
#pragma unroll
      for (int i = 0; i < 4; ++i)
#pragma unroll
        for (int j = 0; j < 4; ++j)
          acc[i][j] = __builtin_amdgcn_mfma_f32_16x16x32_bf16(a[i], b1[j], acc[i][j], 0, 0, 0);
    }
  };

  // ---- prologue: stage As(0) ----
  load_adj(0);
  write_as(As0);
  asm volatile("s_waitcnt lgkmcnt(0)" ::: "memory");
  __builtin_amdgcn_s_barrier();
  asm volatile("" ::: "memory");

  // ---- main loop: lgkm-only barrier per tile ----
  for (int t = 0; t < 63; ++t) {
    const int cur = t & 1;
    const char* Ac = cur ? As1 : As0;
    char* An = cur ? As0 : As1;

    load_adj((t + 1) * 64);  // NT stream, consumed by write_as after compute
    compute(Ac, t);          // B from L2 (sequential block), A from LDS
    write_as(An);            // WAR-safe: An's readers finished at previous barrier
    asm volatile("s_waitcnt lgkmcnt(0)" ::: "memory");  // publish ds_write only
    __builtin_amdgcn_s_barrier();
    asm volatile("" ::: "memory");
  }
  compute(As1, 63);          // t=63

  // ---- degree: 8 partials per row, shfl + LDS exchange (reuse As region) ----
  float d = pdeg;
  d += __shfl_xor(d, 1, 64);
  d += __shfl_xor(d, 2, 64);
  d += __shfl_xor(d, 4, 64);
  __syncthreads();  // all compute done; As region free for reuse
  if ((tid & 7) == 0) reinterpret_cast<float*>(lds)[arow] = d;
  __syncthreads();
  const float* degf = reinterpret_cast<const float*>(lds);

  // ---- epilogue: divide, NT store fp32 ----
#pragma unroll
  for (int i = 0; i < 4; ++i) {
    const int rbase = wr * 64 + i * 16 + ((lane >> 4) << 2);
    float rd[4];
#pragma unroll
    for (int r = 0; r < 4; ++r) rd[r] = 1.0f / degf[rbase + r];
#pragma unroll
    for (int j = 0; j < 4; ++j) {
      const int o = wc * 64 + j * 16 + (lane & 15);
#pragma unroll
      for (int r = 0; r < 4; ++r)
        __builtin_nontemporal_store(acc[i][j][r] * rd[r],
                                    &outb[(size_t)(m0 + rbase + r) * 512 + o]);
    }
  }
}

extern "C" void kernel_launch(void* const* d_in, const int* in_sizes, int n_in,
                              void* d_out, int out_size, void* d_ws, size_t ws_size,
                              hipStream_t stream) {
  (void)in_sizes; (void)n_in; (void)out_size; (void)ws_size;
  const float* X    = (const float*)d_in[0];  // [8,4096,512]
  const float* adj  = (const float*)d_in[1];  // [8,4096,4096]
  const float* W    = (const float*)d_in[2];  // [512,512]
  const float* bias = (const float*)d_in[3];  // [512]
  float* out = (float*)d_out;                 // [8,4096,512] fp32

  char* ws = (char*)d_ws;
  __bf16* hTT = (__bf16*)ws;                                  // 32 MiB (m-blocked)
  __bf16* Wt  = (__bf16*)(ws + (size_t)32 * 1024 * 1024);     // 512 KiB

  k_wt<<<dim3(8, 8), 256, 0, stream>>>(W, Wt);
  k_proj<<<dim3(4, 256), 256, 0, stream>>>(X, Wt, bias, hTT);
  k_agg<<<dim3(256), 1024, 0, stream>>>(adj, hTT, out);
}

// Round 15
// 235.272 us; speedup vs baseline: 1.6782x; 1.6585x over previous
//
#include <hip/hip_runtime.h>
#include <stdint.h>

// out = (adj @ (X@W + b)) / rowsum(adj)
// B=8, N=4096, C_IN=C_OUT=512, all fp32 in/out. bf16 MFMA internally.
// ws: hT bf16 [8][512][4096] (32 MiB), Wt bf16 [512][512] after.
//
// ROOFLINE NOTE (R15): empirical per-CU VMEM law ~13 B/cy/CU (R8 vs R12-14 A/B:
// 96 KiB/tile -> 7.4k cy, 160 KiB/tile -> 13.1k cy, schedule-insensitive).
// k_agg floor = 1.5 GiB total VMEM (adj 512M once + B 1G = 4MiB slice x 32 CUs
// + out 64M) -> ~190-200 us. This kernel (R8 structure) measures ~196 us k_agg.

typedef __attribute__((ext_vector_type(4))) float  f32x4;
typedef __attribute__((ext_vector_type(8))) __bf16 bf16x8;
typedef __attribute__((ext_vector_type(4))) __bf16 bf16x4;

#define GLOAD_LDS16(gsrc, ldst)                                                           \
  __builtin_amdgcn_global_load_lds((const __attribute__((address_space(1))) void*)(gsrc), \
                                   (__attribute__((address_space(3))) void*)(ldst), 16, 0, 0)

#define BARRIER                                  \
  do {                                           \
    asm volatile("" ::: "memory");               \
    __builtin_amdgcn_s_barrier();                \
    asm volatile("" ::: "memory");               \
  } while (0)

// ---------------- K0: Wt[n][k] = bf16(W[k][n]), 512x512 ----------------
__global__ void __launch_bounds__(256) k_wt(const float* __restrict__ W,
                                            __bf16* __restrict__ Wt) {
  __shared__ __bf16 t[64][65];
  const int k0 = blockIdx.x * 64, n0 = blockIdx.y * 64;
  const int tid = threadIdx.x;
  const int r = tid >> 2, c4 = (tid & 3) * 16;
#pragma unroll
  for (int j = 0; j < 4; ++j) {
    f32x4 v = *reinterpret_cast<const f32x4*>(W + (size_t)(k0 + r) * 512 + n0 + c4 + j * 4);
#pragma unroll
    for (int q = 0; q < 4; ++q) t[c4 + j * 4 + q][r] = (__bf16)v[q];
  }
  __syncthreads();
#pragma unroll
  for (int j = 0; j < 4; ++j) {
    bf16x4 o;
#pragma unroll
    for (int q = 0; q < 4; ++q) o[q] = t[r][c4 + j * 4 + q];
    *reinterpret_cast<bf16x4*>(Wt + (size_t)(n0 + r) * 512 + k0 + c4 + j * 4) = o;
  }
}

// ---------------- K1: proj  h = X@W + b, stored transposed as hT[b][o][m] bf16 -----
__global__ void __launch_bounds__(256) k_proj(const float* __restrict__ X,
                                              const __bf16* __restrict__ Wt,
                                              const float* __restrict__ bias,
                                              __bf16* __restrict__ hT) {
  __shared__ __attribute__((aligned(16))) __bf16 Xs[128][72];
  __shared__ __attribute__((aligned(16))) __bf16 Ws[128][72];
  const int n0 = blockIdx.x * 128;
  const int m0 = blockIdx.y * 128;
  const int tid = threadIdx.x;
  const int lane = tid & 63, w = tid >> 6;
  const int wr = w >> 1, wc = w & 1;
  const int srow = tid >> 1, scb = (tid & 1) * 32;

  f32x4 acc[4][4] = {};

  for (int k0 = 0; k0 < 512; k0 += 64) {
    const float* xp = X + (size_t)(m0 + srow) * 512 + k0 + scb;
    f32x4 xv[8];
#pragma unroll
    for (int j = 0; j < 8; ++j) xv[j] = *reinterpret_cast<const f32x4*>(xp + j * 4);
#pragma unroll
    for (int q = 0; q < 4; ++q) {
      bf16x8 o;
#pragma unroll
      for (int e = 0; e < 8; ++e) { const int idx = q * 8 + e; o[e] = (__bf16)xv[idx >> 2][idx & 3]; }
      *reinterpret_cast<bf16x8*>(&Xs[srow][scb + q * 8]) = o;
    }
    const __bf16* wp = Wt + (size_t)(n0 + srow) * 512 + k0 + scb;
#pragma unroll
    for (int q = 0; q < 4; ++q)
      *reinterpret_cast<bf16x8*>(&Ws[srow][scb + q * 8]) =
          *reinterpret_cast<const bf16x8*>(wp + q * 8);
    __syncthreads();

    for (int kk = 0; kk < 64; kk += 32) {
      const int ko = kk + ((lane >> 4) << 3);
      bf16x8 a[4], bb[4];
#pragma unroll
      for (int i = 0; i < 4; ++i)
        a[i] = *reinterpret_cast<const bf16x8*>(&Xs[wr * 64 + i * 16 + (lane & 15)][ko]);
#pragma unroll
      for (int j = 0; j < 4; ++j)
        bb[j] = *reinterpret_cast<const bf16x8*>(&Ws[wc * 64 + j * 16 + (lane & 15)][ko]);
#pragma unroll
      for (int i = 0; i < 4; ++i)
#pragma unroll
        for (int j = 0; j < 4; ++j)
          acc[i][j] = __builtin_amdgcn_mfma_f32_16x16x32_bf16(a[i], bb[j], acc[i][j], 0, 0, 0);
    }
    __syncthreads();
  }

  float bj[4];
#pragma unroll
  for (int j = 0; j < 4; ++j) bj[j] = bias[n0 + wc * 64 + j * 16 + (lane & 15)];
  const int batch = m0 >> 12;
  const int mloc0 = (m0 & 4095) + wr * 64;
#pragma unroll
  for (int i = 0; i < 4; ++i) {
    const int m_in = mloc0 + i * 16 + ((lane >> 4) << 2);
#pragma unroll
    for (int j = 0; j < 4; ++j) {
      const int n = n0 + wc * 64 + j * 16 + (lane & 15);
      bf16x4 o;
#pragma unroll
      for (int r = 0; r < 4; ++r) o[r] = (__bf16)(acc[i][j][r] + bj[j]);
      *reinterpret_cast<bf16x4*>(hT + ((size_t)batch * 512 + n) * 4096 + m_in) = o;
    }
  }
}

// ---------------- K2: aggregation, 16-wave race-free single-barrier pipeline -------
// BM=128 x BN=512 (adj read once), BK=64, 16 waves (2x8), wave tile 64x64.
// As dbuf 2x16K + Hs dbuf 2x64K = 160 KiB, 16 waves/CU (VGPR<=128 band).
// WAR-safe ordering (R7 lesson): prefetch into buffers [1-cur] is issued AFTER
// the barrier (their readers all finished at that barrier). Per tile:
// BARRIER -> issue adj+Hs(t+1) -> compute(cur) -> write_as -> vmcnt(0) [only
// the 4 Hs gloads remain, issued a full compute-phase earlier] -> lgkm(0) -> BARRIER.
// Inside compute: no manual drains/setprio -- compiler emits counted lgkmcnt
// and pipelines ds_reads under MFMAs.
__global__ void __launch_bounds__(1024, 4) k_agg(const float* __restrict__ adj,
                                                 const __bf16* __restrict__ hT,
                                                 float* __restrict__ out) {
  __shared__ __attribute__((aligned(16))) char lds[163840];
  char* As0 = lds;
  char* As1 = lds + 16384;
  char* Hs0 = lds + 32768;
  char* Hs1 = lds + 98304;

  const int bx = ((int)blockIdx.x & 7) * 32 + ((int)blockIdx.x >> 3);  // XCD x <-> batch x
  const int batch = bx >> 5;
  const int m0 = (bx & 31) * 128;
  const int tid = threadIdx.x;
  const int lane = tid & 63, w = tid >> 6;
  const int wr = w >> 3, wc = w & 7;  // wave tile: rows wr*64, cols wc*64

  const float*  adjb = adj + (size_t)batch * 4096 * 4096;
  const __bf16* hTb  = hT + (size_t)batch * 512 * 4096;
  float* outb = out + (size_t)batch * 4096 * 512;

  // A staging: thread -> row tid>>3, 8 cols from (tid&7)*8, XOR-swizzled write
  const int arow = tid >> 3;
  const int acb  = (tid & 7) * 8;
  const int aw   = arow * 128 + (((acb * 2)) ^ ((arow & 7) << 4));
  const float* adjrow = adjb + (size_t)(m0 + arow) * 4096 + acb;

  // Hs gload source pre-swizzle (verified): lane writes 16B block (l&7) of row l>>3
  const int srcblk = (((lane & 7) ^ ((lane >> 3) & 7)) << 3);
  const int hrow_l = (lane >> 3);

  // fragment read swizzle
  const int koffbase = (lane >> 4) << 3;
  const int kswz = (lane & 7) << 4;

  f32x4 acc[4][4] = {};
  float pdeg = 0.f;
  f32x4 av[2];

  auto load_adj = [&](int k0) {  // non-temporal: single-use, protect hT L2 residency
    av[0] = __builtin_nontemporal_load(reinterpret_cast<const f32x4*>(adjrow + k0));
    av[1] = __builtin_nontemporal_load(reinterpret_cast<const f32x4*>(adjrow + k0 + 4));
  };
  auto issue_hs = [&](int k0, char* Hn) {  // 4 chunks of 1 KiB per wave (64 chunks)
#pragma unroll
    for (int q = 0; q < 4; ++q) {
      const int c = w * 4 + q;
      const __bf16* src = hTb + (size_t)(c * 8 + hrow_l) * 4096 + k0 + srcblk;
      GLOAD_LDS16(src, Hn + c * 1024);
    }
  };
  auto write_as = [&](char* An) {  // compiler inserts precise vmcnt for av
    bf16x8 o0;
#pragma unroll
    for (int e = 0; e < 8; ++e) o0[e] = (__bf16)av[e >> 2][e & 3];
    float s = 0.f;
#pragma unroll
    for (int e = 0; e < 8; ++e) s += av[e >> 2][e & 3];
    pdeg += s;
    *reinterpret_cast<bf16x8*>(An + aw) = o0;
  };
  auto compute = [&](const char* Ac, const char* Hc) {
#pragma unroll
    for (int kk = 0; kk < 64; kk += 32) {
      const int ko2 = ((kk + koffbase) * 2) ^ kswz;
      bf16x8 a[4], bb[4];
#pragma unroll
      for (int i = 0; i < 4; ++i) {
        const int row = wr * 64 + i * 16 + (lane & 15);
        a[i] = *reinterpret_cast<const bf16x8*>(Ac + row * 128 + ko2);
      }
#pragma unroll
      for (int j = 0; j < 4; ++j) {
        const int orow = wc * 64 + j * 16 + (lane & 15);
        bb[j] = *reinterpret_cast<const bf16x8*>(Hc + orow * 128 + ko2);
      }
#pragma unroll
      for (int i = 0; i < 4; ++i)
#pragma unroll
        for (int j = 0; j < 4; ++j)
          acc[i][j] = __builtin_amdgcn_mfma_f32_16x16x32_bf16(a[i], bb[j], acc[i][j], 0, 0, 0);
    }
  };

  // ---- prologue: stage tile 0 fully, publish ----
  load_adj(0);
  issue_hs(0, Hs0);
  write_as(As0);
  asm volatile("s_waitcnt vmcnt(0)" ::: "memory");
  asm volatile("s_waitcnt lgkmcnt(0)" ::: "memory");
  BARRIER;

  // ---- main loop: 1 barrier per tile, prefetch issued AFTER the barrier ----
  for (int t = 0; t < 63; ++t) {
    const int cur = t & 1;
    const char* Ac = cur ? As1 : As0;
    const char* Hc = cur ? Hs1 : Hs0;
    char* An = cur ? As0 : As1;
    char* Hn = cur ? Hs0 : Hs1;

    load_adj((t + 1) * 64);       // register loads: no LDS hazard
    issue_hs((t + 1) * 64, Hn);   // WAR-safe: Hn's readers finished at last barrier
    compute(Ac, Hc);              // overlaps the 6 in-flight VMEM
    write_as(An);                 // WAR-safe same way; waits adj (precise vmcnt)
    asm volatile("s_waitcnt vmcnt(0)" ::: "memory");   // only 4 Hs gloads left; short wait
    asm volatile("s_waitcnt lgkmcnt(0)" ::: "memory"); // own ds_write drained
    BARRIER;                      // tile t+1 buffers published
  }

  // ---- last tile (t=63, buffers idx 1) ----
  compute(As1, Hs1);

  // ---- degree: 8 partials per row (threads tid>>3 equal), shfl + reused LDS ----
  float d = pdeg;
  d += __shfl_xor(d, 1, 64);
  d += __shfl_xor(d, 2, 64);
  d += __shfl_xor(d, 4, 64);
  __syncthreads();  // all compute done; As region free for reuse
  if ((tid & 7) == 0) reinterpret_cast<float*>(lds)[arow] = d;
  __syncthreads();
  const float* degf = reinterpret_cast<const float*>(lds);

  // ---- epilogue: divide, NT store fp32 ----
#pragma unroll
  for (int i = 0; i < 4; ++i) {
    const int rbase = wr * 64 + i * 16 + ((lane >> 4) << 2);
    float rd[4];
#pragma unroll
    for (int r = 0; r < 4; ++r) rd[r] = 1.0f / degf[rbase + r];
#pragma unroll
    for (int j = 0; j < 4; ++j) {
      const int o = wc * 64 + j * 16 + (lane & 15);
#pragma unroll
      for (int r = 0; r < 4; ++r)
        __builtin_nontemporal_store(acc[i][j][r] * rd[r],
                                    &outb[(size_t)(m0 + rbase + r) * 512 + o]);
    }
  }
}

extern "C" void kernel_launch(void* const* d_in, const int* in_sizes, int n_in,
                              void* d_out, int out_size, void* d_ws, size_t ws_size,
                              hipStream_t stream) {
  (void)in_sizes; (void)n_in; (void)out_size; (void)ws_size;
  const float* X    = (const float*)d_in[0];  // [8,4096,512]
  const float* adj  = (const float*)d_in[1];  // [8,4096,4096]
  const float* W    = (const float*)d_in[2];  // [512,512]
  const float* bias = (const float*)d_in[3];  // [512]
  float* out = (float*)d_out;                 // [8,4096,512] fp32

  char* ws = (char*)d_ws;
  __bf16* hT = (__bf16*)ws;                                   // 32 MiB
  __bf16* Wt = (__bf16*)(ws + (size_t)32 * 1024 * 1024);      // 512 KiB

  k_wt<<<dim3(8, 8), 256, 0, stream>>>(W, Wt);
  k_proj<<<dim3(4, 256), 256, 0, stream>>>(X, Wt, bias, hT);
  k_agg<<<dim3(256), 1024, 0, stream>>>(adj, hT, out);
}